// Round 1
// baseline (248.139 us; speedup 1.0000x reference)
//
#include <hip/hip_runtime.h>
#include <hip/hip_fp16.h>

#define N_NODES 100000
#define N_EDGES 3200000
#define F_IN    128
#define F_HID   32

#define BSHIFT  7
#define BKSZ    128                               // nodes per bucket
#define NBKT    ((N_NODES + BKSZ - 1) / BKSZ)     // 782
#define CAP     4608                              // bucket capacity: mean 4092 + 8 sigma
#define CHUNK   4096                              // edges per partition block
#define NBLK_E  ((N_EDGES + CHUNK - 1) / CHUNK)   // 782
#define RBITS   17                                // row id bits (100000 < 2^17)
#define RMASK   0x1FFFF

// fast tanh: 1 - 2/(exp2(x*2/ln2)+1). v_exp_f32 + v_rcp_f32 are ~1ulp approx
// -> abs err ~1e-6, far under the fp16-storage error budget (absmax ~1e-3).
// Saturates correctly: x->+inf: exp2->inf, rcp->0, result 1; x->-inf: result -1.
__device__ __forceinline__ float fast_tanh(float x) {
    float t = __builtin_amdgcn_exp2f(x * 2.88539008f);   // e^{2x}
    return 1.0f - 2.0f * __builtin_amdgcn_rcpf(t + 1.0f);
}

// ---------------- coarse partition (fixed-capacity buckets, relative cursors) ----------------
// gcur[] zeroed by hipMemsetAsync; holds per-bucket edge count after k_part.

__global__ __launch_bounds__(512) void k_part(const int* __restrict__ row, const int* __restrict__ col,
                                              int* __restrict__ gcur, unsigned* __restrict__ bkt) {
    __shared__ int hist[NBKT];
    __shared__ int lbase[NBKT];          // local (block) exclusive prefix
    __shared__ int gbase[NBKT];          // global destination base (absolute)
    __shared__ unsigned perm[CHUNK];     // 16 KB: packed words, bucket-major
    __shared__ unsigned short pb[CHUNK]; // 8 KB: bucket id per slot
    __shared__ int wt[8];
    int t = threadIdx.x;
    for (int i = t; i < NBKT; i += 512) hist[i] = 0;
    __syncthreads();

    int e0 = blockIdx.x * CHUNK;
    int n  = min(CHUNK, N_EDGES - e0);
    int r[8], c[8], rk[8];
#pragma unroll
    for (int k = 0; k < 8; k++) {
        int idx = t + k * 512;
        if (idx < n) {
            r[k]  = row[e0 + idx];
            c[k]  = col[e0 + idx];
            rk[k] = atomicAdd(&hist[c[k] >> BSHIFT], 1);   // local rank in bucket
        }
    }
    __syncthreads();

    // block scan: each thread owns 2 consecutive buckets
    {
        int b0 = t * 2;
        int s0 = (b0     < NBKT) ? hist[b0]     : 0;
        int s1 = (b0 + 1 < NBKT) ? hist[b0 + 1] : 0;
        int tsum = s0 + s1;
        int lane = t & 63, wid = t >> 6;
        int incl = tsum;
#pragma unroll
        for (int sh = 1; sh < 64; sh <<= 1) {
            int u = __shfl_up(incl, sh);
            if (lane >= sh) incl += u;
        }
        if (lane == 63) wt[wid] = incl;
        __syncthreads();
        int wpre = 0;
        for (int w = 0; w < wid; w++) wpre += wt[w];
        int excl = wpre + incl - tsum;
        if (b0     < NBKT) lbase[b0]     = excl;
        if (b0 + 1 < NBKT) lbase[b0 + 1] = excl + s0;
    }
    for (int i = t; i < NBKT; i += 512) {
        int h = hist[i];
        gbase[i] = i * CAP + (h ? atomicAdd(&gcur[i], h) : 0);
    }
    __syncthreads();

#pragma unroll
    for (int k = 0; k < 8; k++) {
        int idx = t + k * 512;
        if (idx < n) {
            int b   = c[k] >> BSHIFT;
            int pos = lbase[b] + rk[k];
            perm[pos] = (unsigned)r[k] | ((unsigned)(c[k] & (BKSZ - 1)) << RBITS);
            pb[pos]   = (unsigned short)b;
        }
    }
    __syncthreads();

    for (int i = t; i < n; i += 512) {
        int b = pb[i];
        bkt[gbase[b] + (i - lbase[b])] = perm[i];
    }
}

// ---------------- per-bucket fine sort, IN PLACE (LDS staging), + off/end/dinv ----------------

__global__ __launch_bounds__(1024) void k_bucket(unsigned* __restrict__ bkt,  // in: bkt, out: srt (aliased)
                                                 const int* __restrict__ gcur,
                                                 int* __restrict__ off, int* __restrict__ end,
                                                 float* __restrict__ dinv) {
    __shared__ unsigned stg[CAP];   // 18.4 KB staging
    __shared__ int cnt[BKSZ];
    __shared__ int cur[BKSZ];
    __shared__ int wtot[2];
    int t = threadIdx.x, b = blockIdx.x;
    int s = b * CAP, m = gcur[b];   // gcur holds the bucket count
    if (t < BKSZ) cnt[t] = 0;
    __syncthreads();
    for (int i = t; i < m; i += 1024) {
        unsigned x = bkt[s + i];
        stg[i] = x;
        atomicAdd(&cnt[x >> RBITS], 1);
    }
    __syncthreads();

    int lane = t & 63, wid = t >> 6;
    int v = 0, incl = 0;
    if (t < BKSZ) {
        v = cnt[t];
        incl = v;
        #pragma unroll
        for (int sh = 1; sh < 64; sh <<= 1) {
            int u = __shfl_up(incl, sh);
            if (lane >= sh) incl += u;
        }
        if (lane == 63) wtot[wid] = incl;
    }
    __syncthreads();
    if (t < BKSZ) {
        int wpre = (wid == 1) ? wtot[0] : 0;
        int excl = wpre + incl - v;
        cur[t] = s + excl;
        int g = b * BKSZ + t;
        if (g < N_NODES) {
            off[g]  = s + excl;
            end[g]  = s + excl + v;
            dinv[g] = rsqrtf((float)(v + 1));   // +1 self-loop
        }
    }
    __syncthreads();
    for (int i = t; i < m; i += 1024) {
        unsigned x = stg[i];
        int p = atomicAdd(&cur[x >> RBITS], 1);
        bkt[p] = x & RMASK;   // srt: row ids grouped by dest node
    }
}

// ---------------- h1s = fp16( dinv[r] * (x @ W1)[r] ), 4 feats/thread, ds_read_b128 ----------------

__global__ __launch_bounds__(256) void k_gemm1(const float* __restrict__ x, const float* __restrict__ W1,
                                               const float* __restrict__ dinv, unsigned* __restrict__ h1s) {
    __shared__ float Wlds[F_IN * F_HID];  // 16 KB, [k][f]
    int t = threadIdx.x;
    for (int i = t; i < F_IN * F_HID; i += 256) Wlds[i] = W1[i];
    __syncthreads();

    int gid = blockIdx.x * 256 + t;   // gid = r*8 + f4 ; feats 4f4..4f4+3
    int r = gid >> 3, f4 = gid & 7;
    if (r >= N_NODES) return;

    const float4* x4  = (const float4*)(x + (size_t)r * F_IN);
    const float4* Wl4 = (const float4*)Wlds;   // [(k)*8 + f4]
    float ax = 0.f, ay = 0.f, az = 0.f, aw = 0.f;
#pragma unroll
    for (int k4 = 0; k4 < F_IN / 4; k4++) {
        float4 xv = x4[k4];
        float4 w0 = Wl4[(4 * k4 + 0) * 8 + f4];
        ax += xv.x * w0.x; ay += xv.x * w0.y; az += xv.x * w0.z; aw += xv.x * w0.w;
        float4 w1 = Wl4[(4 * k4 + 1) * 8 + f4];
        ax += xv.y * w1.x; ay += xv.y * w1.y; az += xv.y * w1.z; aw += xv.y * w1.w;
        float4 w2 = Wl4[(4 * k4 + 2) * 8 + f4];
        ax += xv.z * w2.x; ay += xv.z * w2.y; az += xv.z * w2.z; aw += xv.z * w2.w;
        float4 w3 = Wl4[(4 * k4 + 3) * 8 + f4];
        ax += xv.w * w3.x; ay += xv.w * w3.y; az += xv.w * w3.z; aw += xv.w * w3.w;
    }
    float di = dinv[r];
    unsigned p01 = (unsigned)__half_as_ushort(__float2half(di * ax))
                 | ((unsigned)__half_as_ushort(__float2half(di * ay)) << 16);
    unsigned p23 = (unsigned)__half_as_ushort(__float2half(di * az))
                 | ((unsigned)__half_as_ushort(__float2half(di * aw)) << 16);
    ((uint2*)h1s)[(size_t)r * 8 + f4] = make_uint2(p01, p23);
}

// ---------------- conv1: one wave per dest node, uint2 gathers, 4x unroll = 32 edges in flight ----
// R12: fast_tanh (v_exp+v_rcp, ~1e-6 err), 4 accumulator sets (named vars -> no scratch, R11 lesson),
// self-loop gather hoisted above the loop, 2nd butterfly cut 6->4 levels (lanes 0..15 span each
// (o,pp) combo exactly once -> m=1,2,4,8 yields the exact sum; the old x0.25 trick is gone),
// 32-bit byte offsets so gathers take the saddr+voffset global_load form.
// h2s4[c*4+j] = dinv[c] * (tanh(dinv[c]*(Σ_nb h1s[r] + h1s[c])) @ W2)[j], slot 3 = 0

__global__ __launch_bounds__(256) void k_conv1(const int* __restrict__ off, const int* __restrict__ end,
                                               const int* __restrict__ srt, const float* __restrict__ dinv,
                                               const unsigned* __restrict__ h1s,
                                               const float* __restrict__ W2, float* __restrict__ h2s4) {
    int wid  = threadIdx.x >> 6;
    int lane = threadIdx.x & 63;
    int c = blockIdx.x * 4 + wid;
    if (c >= N_NODES) return;
    int o = lane & 7;       // feat-quad: feats [4o, 4o+4)
    int q = lane >> 3;      // edge slot (8 slots; 4x unroll -> 32 edges in flight)
    int pp = q & 1;         // which feature pair of the quad this lane finalizes
    int fA = 4 * o + 2 * pp, fB = fA + 1;

    float wA0 = W2[fA * 3 + 0], wA1 = W2[fA * 3 + 1], wA2 = W2[fA * 3 + 2];
    float wB0 = W2[fB * 3 + 0], wB1 = W2[fB * 3 + 1], wB2 = W2[fB * 3 + 2];

    int b = off[c], e = end[c];
    float di = dinv[c];

    const char* h1b = (const char*)h1s;
    unsigned oo = (unsigned)(o << 3);
    // self-loop row: independent load, issue before the gather loop
    uint2 sv = *(const uint2*)(h1b + (((unsigned)c << 6) + oo));

    __half2 z = __float2half2_rn(0.0f);
    __half2 s01a = z, s23a = z, s01b = z, s23b = z;
    __half2 s01c = z, s23c = z, s01d = z, s23d = z;
    int p = b + q;
    for (; p + 24 < e; p += 32) {
        int r0 = srt[p];
        int r1 = srt[p + 8];
        int r2 = srt[p + 16];
        int r3 = srt[p + 24];
        uint2 v0 = *(const uint2*)(h1b + (((unsigned)r0 << 6) + oo));
        uint2 v1 = *(const uint2*)(h1b + (((unsigned)r1 << 6) + oo));
        uint2 v2 = *(const uint2*)(h1b + (((unsigned)r2 << 6) + oo));
        uint2 v3 = *(const uint2*)(h1b + (((unsigned)r3 << 6) + oo));
        s01a = __hadd2(s01a, *(const __half2*)&v0.x);
        s23a = __hadd2(s23a, *(const __half2*)&v0.y);
        s01b = __hadd2(s01b, *(const __half2*)&v1.x);
        s23b = __hadd2(s23b, *(const __half2*)&v1.y);
        s01c = __hadd2(s01c, *(const __half2*)&v2.x);
        s23c = __hadd2(s23c, *(const __half2*)&v2.y);
        s01d = __hadd2(s01d, *(const __half2*)&v3.x);
        s23d = __hadd2(s23d, *(const __half2*)&v3.y);
    }
    // tail: p+24 >= e here, so at most {p, p+8, p+16} remain per slot
    if (p < e) {
        int r0 = srt[p];
        uint2 v0 = *(const uint2*)(h1b + (((unsigned)r0 << 6) + oo));
        s01a = __hadd2(s01a, *(const __half2*)&v0.x);
        s23a = __hadd2(s23a, *(const __half2*)&v0.y);
    }
    if (p + 8 < e) {
        int r1 = srt[p + 8];
        uint2 v1 = *(const uint2*)(h1b + (((unsigned)r1 << 6) + oo));
        s01b = __hadd2(s01b, *(const __half2*)&v1.x);
        s23b = __hadd2(s23b, *(const __half2*)&v1.y);
    }
    if (p + 16 < e) {
        int r2 = srt[p + 16];
        uint2 v2 = *(const uint2*)(h1b + (((unsigned)r2 << 6) + oo));
        s01c = __hadd2(s01c, *(const __half2*)&v2.x);
        s23c = __hadd2(s23c, *(const __half2*)&v2.y);
    }
    s01a = __hadd2(s01a, s01b);  s23a = __hadd2(s23a, s23b);
    s01c = __hadd2(s01c, s01d);  s23c = __hadd2(s23c, s23d);
    __half2 s01 = __hadd2(s01a, s01c);
    __half2 s23 = __hadd2(s23a, s23c);

    // to f32, butterfly over the 8 edge slots
    float f0 = __low2float(s01), f1 = __high2float(s01);
    float f2v = __low2float(s23), f3 = __high2float(s23);
#pragma unroll
    for (int m = 8; m <= 32; m <<= 1) {
        f0  += __shfl_xor(f0, m);  f1 += __shfl_xor(f1, m);
        f2v += __shfl_xor(f2v, m); f3 += __shfl_xor(f3, m);
    }

    // self-loop term: added ONCE, after the slot reduction (already dinv[c]-scaled)
    f0  += __low2float(*(const __half2*)&sv.x);
    f1  += __high2float(*(const __half2*)&sv.x);
    f2v += __low2float(*(const __half2*)&sv.y);
    f3  += __high2float(*(const __half2*)&sv.y);

    float vA = pp ? f2v : f0;
    float vB = pp ? f3  : f1;
    float hA = fast_tanh(di * vA);
    float hB = fast_tanh(di * vB);

    // each (o,pp) combo appears exactly once in each contiguous 16-lane group
    // -> 4-level butterfly (m=1..8) produces the exact sum on every lane of group 0
    float p0 = hA * wA0 + hB * wB0;
    float p1 = hA * wA1 + hB * wB1;
    float p2 = hA * wA2 + hB * wB2;
#pragma unroll
    for (int m = 1; m <= 8; m <<= 1) {
        p0 += __shfl_xor(p0, m);
        p1 += __shfl_xor(p1, m);
        p2 += __shfl_xor(p2, m);
    }
    if (lane < 4) {
        float vv = (lane == 0) ? p0 : (lane == 1) ? p1 : (lane == 2) ? p2 : 0.0f;
        h2s4[(size_t)c * 4 + lane] = (lane < 3) ? di * vv : 0.0f;  // slot 3 = real 0
    }
}

// ---------------- conv2: one wave per dest node, 64 edges in flight (float4 loads) ----------------
// R12: self term folded into lane 0's accumulator init (removes serialized end-of-kernel read)

__global__ __launch_bounds__(256) void k_conv2(const int* __restrict__ off, const int* __restrict__ end,
                                               const int* __restrict__ srt, const float* __restrict__ dinv,
                                               const float* __restrict__ h2s4, float* __restrict__ out) {
    int wid  = threadIdx.x >> 6;
    int lane = threadIdx.x & 63;
    int c = blockIdx.x * 4 + wid;
    if (c >= N_NODES) return;

    const float4* h2v = (const float4*)h2s4;
    int b = off[c], e = end[c];
    float4 sv = h2v[c];                      // self-loop term (w component = 0)
    float ax = (lane == 0) ? sv.x : 0.0f;
    float ay = (lane == 0) ? sv.y : 0.0f;
    float az = (lane == 0) ? sv.z : 0.0f;
    for (int p = b + lane; p < e; p += 64) {
        int r = srt[p];
        float4 v = h2v[r];
        ax += v.x; ay += v.y; az += v.z;
    }
#pragma unroll
    for (int m = 1; m <= 32; m <<= 1) {
        ax += __shfl_xor(ax, m);
        ay += __shfl_xor(ay, m);
        az += __shfl_xor(az, m);
    }

    float di = dinv[c];
    if (lane < 3) {
        float a = (lane == 0) ? ax : (lane == 1) ? ay : az;
        out[(size_t)c * 3 + lane] = di * a;
    }
}

// ---------------- launch ----------------

extern "C" void kernel_launch(void* const* d_in, const int* in_sizes, int n_in,
                              void* d_out, int out_size, void* d_ws, size_t ws_size,
                              hipStream_t stream) {
    const float* x   = (const float*)d_in[0];
    const int*   ei  = (const int*)d_in[1];  // [2, E] int32
    const float* W1  = (const float*)d_in[2];
    const float* W2  = (const float*)d_in[3];
    float*       out = (float*)d_out;

    const int* row = ei;
    const int* col = ei + N_EDGES;

    char* ws = (char*)d_ws;
    unsigned* bkt = (unsigned*)ws;
    int*      srt = (int*)ws;                 // alias (in-place after k_bucket)
    char*     p   = ws + 4ull * NBKT * CAP;
    int*      gcur = (int*)p;                 p += 4ull * ((NBKT + 63) & ~63);
    int*      off  = (int*)p;                 p += 4ull * N_NODES;
    int*      end  = (int*)p;                 p += 4ull * N_NODES;
    float*    dinv = (float*)p;               p += 4ull * N_NODES;
    unsigned* h1s  = (unsigned*)p;            p += 64ull * N_NODES;
    float*    h2s4 = (float*)p;

    const int B = 256;
    hipMemsetAsync(gcur, 0, 4ull * NBKT, stream);
    hipLaunchKernelGGL(k_part,   dim3(NBLK_E), dim3(512),  0, stream, row, col, gcur, bkt);
    hipLaunchKernelGGL(k_bucket, dim3(NBKT),   dim3(1024), 0, stream, bkt, gcur, off, end, dinv);
    hipLaunchKernelGGL(k_gemm1,  dim3((N_NODES * 8 + B - 1) / B), dim3(B), 0, stream, x, W1, dinv, h1s);
    hipLaunchKernelGGL(k_conv1,  dim3((N_NODES + 3) / 4), dim3(B), 0, stream,
                       off, end, srt, dinv, h1s, W2, h2s4);
    hipLaunchKernelGGL(k_conv2,  dim3((N_NODES + 3) / 4), dim3(B), 0, stream,
                       off, end, srt, dinv, h2s4, out);
}

// Round 2
// 234.669 us; speedup vs baseline: 1.0574x; 1.0574x over previous
//
#include <hip/hip_runtime.h>
#include <hip/hip_fp16.h>

#define N_NODES 100000
#define N_EDGES 3200000
#define F_IN    128
#define F_HID   32

#define BSHIFT  7
#define BKSZ    128                               // nodes per bucket
#define NBKT    ((N_NODES + BKSZ - 1) / BKSZ)     // 782
#define CAP     4608                              // bucket capacity: mean 4092 + 8 sigma
#define CHUNK   4096                              // edges per partition block
#define NBLK_E  ((N_EDGES + CHUNK - 1) / CHUNK)   // 782
#define RBITS   17                                // row id bits (100000 < 2^17)
#define RMASK   0x1FFFF

// fast tanh: 1 - 2/(exp2(x*2/ln2)+1). v_exp_f32 + v_rcp_f32 are ~1ulp approx
// -> abs err ~1e-6, far under the fp16-storage error budget (absmax ~1e-3).
__device__ __forceinline__ float fast_tanh(float x) {
    float t = __builtin_amdgcn_exp2f(x * 2.88539008f);   // e^{2x}
    return 1.0f - 2.0f * __builtin_amdgcn_rcpf(t + 1.0f);
}

// ---------------- coarse partition (fixed-capacity buckets, relative cursors) ----------------
// gcur[] zeroed by hipMemsetAsync; holds per-bucket edge count after k_part.

__global__ __launch_bounds__(512) void k_part(const int* __restrict__ row, const int* __restrict__ col,
                                              int* __restrict__ gcur, unsigned* __restrict__ bkt) {
    __shared__ int hist[NBKT];
    __shared__ int lbase[NBKT];          // local (block) exclusive prefix
    __shared__ int gbase[NBKT];          // global destination base (absolute)
    __shared__ unsigned perm[CHUNK];     // 16 KB: packed words, bucket-major
    __shared__ unsigned short pb[CHUNK]; // 8 KB: bucket id per slot
    __shared__ int wt[8];
    int t = threadIdx.x;
    for (int i = t; i < NBKT; i += 512) hist[i] = 0;
    __syncthreads();

    int e0 = blockIdx.x * CHUNK;
    int n  = min(CHUNK, N_EDGES - e0);
    int r[8], c[8], rk[8];
#pragma unroll
    for (int k = 0; k < 8; k++) {
        int idx = t + k * 512;
        if (idx < n) {
            r[k]  = row[e0 + idx];
            c[k]  = col[e0 + idx];
            rk[k] = atomicAdd(&hist[c[k] >> BSHIFT], 1);   // local rank in bucket
        }
    }
    __syncthreads();

    // block scan: each thread owns 2 consecutive buckets
    {
        int b0 = t * 2;
        int s0 = (b0     < NBKT) ? hist[b0]     : 0;
        int s1 = (b0 + 1 < NBKT) ? hist[b0 + 1] : 0;
        int tsum = s0 + s1;
        int lane = t & 63, wid = t >> 6;
        int incl = tsum;
#pragma unroll
        for (int sh = 1; sh < 64; sh <<= 1) {
            int u = __shfl_up(incl, sh);
            if (lane >= sh) incl += u;
        }
        if (lane == 63) wt[wid] = incl;
        __syncthreads();
        int wpre = 0;
        for (int w = 0; w < wid; w++) wpre += wt[w];
        int excl = wpre + incl - tsum;
        if (b0     < NBKT) lbase[b0]     = excl;
        if (b0 + 1 < NBKT) lbase[b0 + 1] = excl + s0;
    }
    for (int i = t; i < NBKT; i += 512) {
        int h = hist[i];
        gbase[i] = i * CAP + (h ? atomicAdd(&gcur[i], h) : 0);
    }
    __syncthreads();

#pragma unroll
    for (int k = 0; k < 8; k++) {
        int idx = t + k * 512;
        if (idx < n) {
            int b   = c[k] >> BSHIFT;
            int pos = lbase[b] + rk[k];
            perm[pos] = (unsigned)r[k] | ((unsigned)(c[k] & (BKSZ - 1)) << RBITS);
            pb[pos]   = (unsigned short)b;
        }
    }
    __syncthreads();

    for (int i = t; i < n; i += 512) {
        int b = pb[i];
        bkt[gbase[b] + (i - lbase[b])] = perm[i];
    }
}

// ---------------- per-bucket fine sort, IN PLACE (LDS staging), + off/end/dinv ----------------

__global__ __launch_bounds__(1024) void k_bucket(unsigned* __restrict__ bkt,  // in: bkt, out: srt (aliased)
                                                 const int* __restrict__ gcur,
                                                 int* __restrict__ off, int* __restrict__ end,
                                                 float* __restrict__ dinv) {
    __shared__ unsigned stg[CAP];   // 18.4 KB staging
    __shared__ int cnt[BKSZ];
    __shared__ int cur[BKSZ];
    __shared__ int wtot[2];
    int t = threadIdx.x, b = blockIdx.x;
    int s = b * CAP, m = gcur[b];   // gcur holds the bucket count
    if (t < BKSZ) cnt[t] = 0;
    __syncthreads();
    for (int i = t; i < m; i += 1024) {
        unsigned x = bkt[s + i];
        stg[i] = x;
        atomicAdd(&cnt[x >> RBITS], 1);
    }
    __syncthreads();

    int lane = t & 63, wid = t >> 6;
    int v = 0, incl = 0;
    if (t < BKSZ) {
        v = cnt[t];
        incl = v;
        #pragma unroll
        for (int sh = 1; sh < 64; sh <<= 1) {
            int u = __shfl_up(incl, sh);
            if (lane >= sh) incl += u;
        }
        if (lane == 63) wtot[wid] = incl;
    }
    __syncthreads();
    if (t < BKSZ) {
        int wpre = (wid == 1) ? wtot[0] : 0;
        int excl = wpre + incl - v;
        cur[t] = s + excl;
        int g = b * BKSZ + t;
        if (g < N_NODES) {
            off[g]  = s + excl;
            end[g]  = s + excl + v;
            dinv[g] = rsqrtf((float)(v + 1));   // +1 self-loop
        }
    }
    __syncthreads();
    for (int i = t; i < m; i += 1024) {
        unsigned x = stg[i];
        int p = atomicAdd(&cur[x >> RBITS], 1);
        bkt[p] = x & RMASK;   // srt: row ids grouped by dest node
    }
}

// ---------------- h1s = fp16( dinv[r] * (x @ W1)[r] ), 4 feats/thread, ds_read_b128 ----------------
// R13: row N_NODES is an all-zero row (gather target for predicated-off edges in k_conv1)

__global__ __launch_bounds__(256) void k_gemm1(const float* __restrict__ x, const float* __restrict__ W1,
                                               const float* __restrict__ dinv, unsigned* __restrict__ h1s) {
    __shared__ float Wlds[F_IN * F_HID];  // 16 KB, [k][f]
    int t = threadIdx.x;
    for (int i = t; i < F_IN * F_HID; i += 256) Wlds[i] = W1[i];
    __syncthreads();

    int gid = blockIdx.x * 256 + t;   // gid = r*8 + f4 ; feats 4f4..4f4+3
    int r = gid >> 3, f4 = gid & 7;
    if (r > N_NODES) return;
    if (r == N_NODES) {               // zero row for masked gathers
        ((uint2*)h1s)[(size_t)r * 8 + f4] = make_uint2(0u, 0u);
        return;
    }

    const float4* x4  = (const float4*)(x + (size_t)r * F_IN);
    const float4* Wl4 = (const float4*)Wlds;   // [(k)*8 + f4]
    float ax = 0.f, ay = 0.f, az = 0.f, aw = 0.f;
#pragma unroll
    for (int k4 = 0; k4 < F_IN / 4; k4++) {
        float4 xv = x4[k4];
        float4 w0 = Wl4[(4 * k4 + 0) * 8 + f4];
        ax += xv.x * w0.x; ay += xv.x * w0.y; az += xv.x * w0.z; aw += xv.x * w0.w;
        float4 w1 = Wl4[(4 * k4 + 1) * 8 + f4];
        ax += xv.y * w1.x; ay += xv.y * w1.y; az += xv.y * w1.z; aw += xv.y * w1.w;
        float4 w2 = Wl4[(4 * k4 + 2) * 8 + f4];
        ax += xv.z * w2.x; ay += xv.z * w2.y; az += xv.z * w2.z; aw += xv.z * w2.w;
        float4 w3 = Wl4[(4 * k4 + 3) * 8 + f4];
        ax += xv.w * w3.x; ay += xv.w * w3.y; az += xv.w * w3.z; aw += xv.w * w3.w;
    }
    float di = dinv[r];
    unsigned p01 = (unsigned)__half_as_ushort(__float2half(di * ax))
                 | ((unsigned)__half_as_ushort(__float2half(di * ay)) << 16);
    unsigned p23 = (unsigned)__half_as_ushort(__float2half(di * az))
                 | ((unsigned)__half_as_ushort(__float2half(di * aw)) << 16);
    ((uint2*)h1s)[(size_t)r * 8 + f4] = make_uint2(p01, p23);
}

// ---------------- conv1 R13: 8 nodes per wave ----------------
// lane = q*8 + o: slot q (0..7) owns node c = waveBase + q; o (0..7) owns feat quad [4o,4o+4).
// Each lane accumulates its node's 4 features FULLY LOCALLY (f32 accumulators) -> no cross-slot
// butterfly for the conv sum. All slots loop to the max degree of the 8-node group; masked
// edges redirect to the all-zero h1s row N_NODES (exact +0.0). Epilogue: tanh x4, @W2,
// 3-level butterfly over the 8 feat lanes only. 8x fewer waves than one-node-per-wave.

__global__ __launch_bounds__(256) void k_conv1(const int* __restrict__ off, const int* __restrict__ end,
                                               const int* __restrict__ srt, const float* __restrict__ dinv,
                                               const unsigned* __restrict__ h1s,
                                               const float* __restrict__ W2, float* __restrict__ h2s4) {
    int t = threadIdx.x;
    int lane = t & 63, wid = t >> 6;
    int q = lane >> 3, o = lane & 7;
    int c = (blockIdx.x * 4 + wid) * 8 + q;   // grid = N/32 exactly -> c < N_NODES always

    int b = off[c], e = end[c];
    const char* h1b = (const char*)h1s;
    unsigned oo = (unsigned)(o << 3);
    // self-loop row: independent load, issue before the gather loop
    uint2 sv = *(const uint2*)(h1b + (((unsigned)c << 6) + oo));
    int last = (e > b) ? (e - 1) : b;         // safe clamp index (deg-0 slot reads srt[b], in-bounds)

    float a0a = 0.f, a1a = 0.f, a2a = 0.f, a3a = 0.f;
    float a0b = 0.f, a1b = 0.f, a2b = 0.f, a3b = 0.f;
    float a0c = 0.f, a1c = 0.f, a2c = 0.f, a3c = 0.f;
    float a0d = 0.f, a1d = 0.f, a2d = 0.f, a3d = 0.f;

    int p = b;
    while (__any(p < e)) {
        int i0 = min(p,     last);
        int i1 = min(p + 1, last);
        int i2 = min(p + 2, last);
        int i3 = min(p + 3, last);
        int r0 = srt[i0];
        int r1 = srt[i1];
        int r2 = srt[i2];
        int r3 = srt[i3];
        r0 = (p     < e) ? r0 : N_NODES;      // masked -> zero row
        r1 = (p + 1 < e) ? r1 : N_NODES;
        r2 = (p + 2 < e) ? r2 : N_NODES;
        r3 = (p + 3 < e) ? r3 : N_NODES;
        uint2 v0 = *(const uint2*)(h1b + (((unsigned)r0 << 6) + oo));
        uint2 v1 = *(const uint2*)(h1b + (((unsigned)r1 << 6) + oo));
        uint2 v2 = *(const uint2*)(h1b + (((unsigned)r2 << 6) + oo));
        uint2 v3 = *(const uint2*)(h1b + (((unsigned)r3 << 6) + oo));
        a0a += __low2float(*(const __half2*)&v0.x);  a1a += __high2float(*(const __half2*)&v0.x);
        a2a += __low2float(*(const __half2*)&v0.y);  a3a += __high2float(*(const __half2*)&v0.y);
        a0b += __low2float(*(const __half2*)&v1.x);  a1b += __high2float(*(const __half2*)&v1.x);
        a2b += __low2float(*(const __half2*)&v1.y);  a3b += __high2float(*(const __half2*)&v1.y);
        a0c += __low2float(*(const __half2*)&v2.x);  a1c += __high2float(*(const __half2*)&v2.x);
        a2c += __low2float(*(const __half2*)&v2.y);  a3c += __high2float(*(const __half2*)&v2.y);
        a0d += __low2float(*(const __half2*)&v3.x);  a1d += __high2float(*(const __half2*)&v3.x);
        a2d += __low2float(*(const __half2*)&v3.y);  a3d += __high2float(*(const __half2*)&v3.y);
        p += 4;
    }

    float di = dinv[c];
    float f0 = (a0a + a0b) + (a0c + a0d) + __low2float(*(const __half2*)&sv.x);
    float f1 = (a1a + a1b) + (a1c + a1d) + __high2float(*(const __half2*)&sv.x);
    float f2 = (a2a + a2b) + (a2c + a2d) + __low2float(*(const __half2*)&sv.y);
    float f3 = (a3a + a3b) + (a3c + a3d) + __high2float(*(const __half2*)&sv.y);

    float h0 = fast_tanh(di * f0);
    float h1 = fast_tanh(di * f1);
    float h2 = fast_tanh(di * f2);
    float h3 = fast_tanh(di * f3);

    // W2 rows for feats 4o..4o+3 (loaded post-loop to keep loop VGPR pressure low)
    const float* Wp = W2 + (o << 2) * 3;
    float p0 = h0 * Wp[0] + h1 * Wp[3] + h2 * Wp[6] + h3 * Wp[9];
    float p1 = h0 * Wp[1] + h1 * Wp[4] + h2 * Wp[7] + h3 * Wp[10];
    float p2 = h0 * Wp[2] + h1 * Wp[5] + h2 * Wp[8] + h3 * Wp[11];
#pragma unroll
    for (int m = 1; m <= 4; m <<= 1) {       // reduce over the 8 feat lanes (o), within each slot
        p0 += __shfl_xor(p0, m);
        p1 += __shfl_xor(p1, m);
        p2 += __shfl_xor(p2, m);
    }
    if (o < 4) {
        float vv = (o == 0) ? p0 : (o == 1) ? p1 : (o == 2) ? p2 : 0.0f;
        h2s4[(size_t)c * 4 + o] = (o < 3) ? di * vv : 0.0f;   // slot 3 = real 0
    }
}

// ---------------- conv2: one wave per dest node, 64 edges in flight (float4 loads) ----------------

__global__ __launch_bounds__(256) void k_conv2(const int* __restrict__ off, const int* __restrict__ end,
                                               const int* __restrict__ srt, const float* __restrict__ dinv,
                                               const float* __restrict__ h2s4, float* __restrict__ out) {
    int wid  = threadIdx.x >> 6;
    int lane = threadIdx.x & 63;
    int c = blockIdx.x * 4 + wid;
    if (c >= N_NODES) return;

    const float4* h2v = (const float4*)h2s4;
    int b = off[c], e = end[c];
    float4 sv = h2v[c];                      // self-loop term (w component = 0)
    float ax = (lane == 0) ? sv.x : 0.0f;
    float ay = (lane == 0) ? sv.y : 0.0f;
    float az = (lane == 0) ? sv.z : 0.0f;
    for (int p = b + lane; p < e; p += 64) {
        int r = srt[p];
        float4 v = h2v[r];
        ax += v.x; ay += v.y; az += v.z;
    }
#pragma unroll
    for (int m = 1; m <= 32; m <<= 1) {
        ax += __shfl_xor(ax, m);
        ay += __shfl_xor(ay, m);
        az += __shfl_xor(az, m);
    }

    float di = dinv[c];
    if (lane < 3) {
        float a = (lane == 0) ? ax : (lane == 1) ? ay : az;
        out[(size_t)c * 3 + lane] = di * a;
    }
}

// ---------------- launch ----------------

extern "C" void kernel_launch(void* const* d_in, const int* in_sizes, int n_in,
                              void* d_out, int out_size, void* d_ws, size_t ws_size,
                              hipStream_t stream) {
    const float* x   = (const float*)d_in[0];
    const int*   ei  = (const int*)d_in[1];  // [2, E] int32
    const float* W1  = (const float*)d_in[2];
    const float* W2  = (const float*)d_in[3];
    float*       out = (float*)d_out;

    const int* row = ei;
    const int* col = ei + N_EDGES;

    char* ws = (char*)d_ws;
    unsigned* bkt = (unsigned*)ws;
    int*      srt = (int*)ws;                 // alias (in-place after k_bucket)
    char*     p   = ws + 4ull * NBKT * CAP;
    int*      gcur = (int*)p;                 p += 4ull * ((NBKT + 63) & ~63);
    int*      off  = (int*)p;                 p += 4ull * N_NODES;
    int*      end  = (int*)p;                 p += 4ull * N_NODES;
    float*    dinv = (float*)p;               p += 4ull * N_NODES;
    unsigned* h1s  = (unsigned*)p;            p += 64ull * (N_NODES + 1);  // +1 zero row
    float*    h2s4 = (float*)p;

    const int B = 256;
    hipMemsetAsync(gcur, 0, 4ull * NBKT, stream);
    hipLaunchKernelGGL(k_part,   dim3(NBLK_E), dim3(512),  0, stream, row, col, gcur, bkt);
    hipLaunchKernelGGL(k_bucket, dim3(NBKT),   dim3(1024), 0, stream, bkt, gcur, off, end, dinv);
    hipLaunchKernelGGL(k_gemm1,  dim3(((N_NODES + 1) * 8 + B - 1) / B), dim3(B), 0, stream, x, W1, dinv, h1s);
    hipLaunchKernelGGL(k_conv1,  dim3(N_NODES / 32), dim3(B), 0, stream,
                       off, end, srt, dinv, h1s, W2, h2s4);
    hipLaunchKernelGGL(k_conv2,  dim3((N_NODES + 3) / 4), dim3(B), 0, stream,
                       off, end, srt, dinv, h2s4, out);
}

// Round 3
// 227.256 us; speedup vs baseline: 1.0919x; 1.0326x over previous
//
#include <hip/hip_runtime.h>
#include <hip/hip_fp16.h>

#define N_NODES 100000
#define N_EDGES 3200000
#define F_IN    128
#define F_HID   32

#define BSHIFT  7
#define BKSZ    128                               // nodes per bucket
#define NBKT    ((N_NODES + BKSZ - 1) / BKSZ)     // 782
#define CAP     4608                              // bucket capacity: mean 4092 + 8 sigma (div by 4)
#define CHUNK   4096                              // edges per partition block
#define NBLK_E  ((N_EDGES + CHUNK - 1) / CHUNK)   // 782
#define RBITS   17                                // row id bits (100000 < 2^17)
#define RMASK   0x1FFFF

// fast tanh: 1 - 2/(exp2(x*2/ln2)+1). v_exp_f32 + v_rcp_f32 are ~1ulp approx
// -> abs err ~1e-6, far under the fp16-storage error budget (absmax ~1e-3).
__device__ __forceinline__ float fast_tanh(float x) {
    float t = __builtin_amdgcn_exp2f(x * 2.88539008f);   // e^{2x}
    return 1.0f - 2.0f * __builtin_amdgcn_rcpf(t + 1.0f);
}

// ---------------- coarse partition (fixed-capacity buckets, relative cursors) ----------------
// gcur[] zeroed by hipMemsetAsync; holds per-bucket edge count after k_part.

__global__ __launch_bounds__(512) void k_part(const int* __restrict__ row, const int* __restrict__ col,
                                              int* __restrict__ gcur, unsigned* __restrict__ bkt) {
    __shared__ int hist[NBKT];
    __shared__ int lbase[NBKT];          // local (block) exclusive prefix
    __shared__ int gbase[NBKT];          // global destination base (absolute)
    __shared__ unsigned perm[CHUNK];     // 16 KB: packed words, bucket-major
    __shared__ unsigned short pb[CHUNK]; // 8 KB: bucket id per slot
    __shared__ int wt[8];
    int t = threadIdx.x;
    for (int i = t; i < NBKT; i += 512) hist[i] = 0;
    __syncthreads();

    int e0 = blockIdx.x * CHUNK;
    int n  = min(CHUNK, N_EDGES - e0);
    int r[8], c[8], rk[8];
#pragma unroll
    for (int k = 0; k < 8; k++) {
        int idx = t + k * 512;
        if (idx < n) {
            r[k]  = row[e0 + idx];
            c[k]  = col[e0 + idx];
            rk[k] = atomicAdd(&hist[c[k] >> BSHIFT], 1);   // local rank in bucket
        }
    }
    __syncthreads();

    // block scan: each thread owns 2 consecutive buckets
    {
        int b0 = t * 2;
        int s0 = (b0     < NBKT) ? hist[b0]     : 0;
        int s1 = (b0 + 1 < NBKT) ? hist[b0 + 1] : 0;
        int tsum = s0 + s1;
        int lane = t & 63, wid = t >> 6;
        int incl = tsum;
#pragma unroll
        for (int sh = 1; sh < 64; sh <<= 1) {
            int u = __shfl_up(incl, sh);
            if (lane >= sh) incl += u;
        }
        if (lane == 63) wt[wid] = incl;
        __syncthreads();
        int wpre = 0;
        for (int w = 0; w < wid; w++) wpre += wt[w];
        int excl = wpre + incl - tsum;
        if (b0     < NBKT) lbase[b0]     = excl;
        if (b0 + 1 < NBKT) lbase[b0 + 1] = excl + s0;
    }
    for (int i = t; i < NBKT; i += 512) {
        int h = hist[i];
        gbase[i] = i * CAP + (h ? atomicAdd(&gcur[i], h) : 0);
    }
    __syncthreads();

#pragma unroll
    for (int k = 0; k < 8; k++) {
        int idx = t + k * 512;
        if (idx < n) {
            int b   = c[k] >> BSHIFT;
            int pos = lbase[b] + rk[k];
            perm[pos] = (unsigned)r[k] | ((unsigned)(c[k] & (BKSZ - 1)) << RBITS);
            pb[pos]   = (unsigned short)b;
        }
    }
    __syncthreads();

    for (int i = t; i < n; i += 512) {
        int b = pb[i];
        bkt[gbase[b] + (i - lbase[b])] = perm[i];
    }
}

// ---------------- per-bucket fine sort, IN PLACE (LDS staging), + off/end/dinv ----------------

__global__ __launch_bounds__(1024) void k_bucket(unsigned* __restrict__ bkt,  // in: bkt, out: srt (aliased)
                                                 const int* __restrict__ gcur,
                                                 int* __restrict__ off, int* __restrict__ end,
                                                 float* __restrict__ dinv) {
    __shared__ unsigned stg[CAP];   // 18.4 KB staging
    __shared__ int cnt[BKSZ];
    __shared__ int cur[BKSZ];
    __shared__ int wtot[2];
    int t = threadIdx.x, b = blockIdx.x;
    int s = b * CAP, m = gcur[b];   // gcur holds the bucket count
    if (t < BKSZ) cnt[t] = 0;
    __syncthreads();
    for (int i = t; i < m; i += 1024) {
        unsigned x = bkt[s + i];
        stg[i] = x;
        atomicAdd(&cnt[x >> RBITS], 1);
    }
    __syncthreads();

    int lane = t & 63, wid = t >> 6;
    int v = 0, incl = 0;
    if (t < BKSZ) {
        v = cnt[t];
        incl = v;
        #pragma unroll
        for (int sh = 1; sh < 64; sh <<= 1) {
            int u = __shfl_up(incl, sh);
            if (lane >= sh) incl += u;
        }
        if (lane == 63) wtot[wid] = incl;
    }
    __syncthreads();
    if (t < BKSZ) {
        int wpre = (wid == 1) ? wtot[0] : 0;
        int excl = wpre + incl - v;
        cur[t] = s + excl;
        int g = b * BKSZ + t;
        if (g < N_NODES) {
            off[g]  = s + excl;
            end[g]  = s + excl + v;
            dinv[g] = rsqrtf((float)(v + 1));   // +1 self-loop
        }
    }
    __syncthreads();
    for (int i = t; i < m; i += 1024) {
        unsigned x = stg[i];
        int p = atomicAdd(&cur[x >> RBITS], 1);
        bkt[p] = x & RMASK;   // srt: row ids grouped by dest node
    }
}

// ---------------- h1s = fp16( dinv[r] * (x @ W1)[r] ), 4 feats/thread, ds_read_b128 ----------------
// Row N_NODES is an all-zero row (gather target for predicated-off edges in k_conv1)

__global__ __launch_bounds__(256) void k_gemm1(const float* __restrict__ x, const float* __restrict__ W1,
                                               const float* __restrict__ dinv, unsigned* __restrict__ h1s) {
    __shared__ float Wlds[F_IN * F_HID];  // 16 KB, [k][f]
    int t = threadIdx.x;
    for (int i = t; i < F_IN * F_HID; i += 256) Wlds[i] = W1[i];
    __syncthreads();

    int gid = blockIdx.x * 256 + t;   // gid = r*8 + f4 ; feats 4f4..4f4+3
    int r = gid >> 3, f4 = gid & 7;
    if (r > N_NODES) return;
    if (r == N_NODES) {               // zero row for masked gathers
        ((uint2*)h1s)[(size_t)r * 8 + f4] = make_uint2(0u, 0u);
        return;
    }

    const float4* x4  = (const float4*)(x + (size_t)r * F_IN);
    const float4* Wl4 = (const float4*)Wlds;   // [(k)*8 + f4]
    float ax = 0.f, ay = 0.f, az = 0.f, aw = 0.f;
#pragma unroll
    for (int k4 = 0; k4 < F_IN / 4; k4++) {
        float4 xv = x4[k4];
        float4 w0 = Wl4[(4 * k4 + 0) * 8 + f4];
        ax += xv.x * w0.x; ay += xv.x * w0.y; az += xv.x * w0.z; aw += xv.x * w0.w;
        float4 w1 = Wl4[(4 * k4 + 1) * 8 + f4];
        ax += xv.y * w1.x; ay += xv.y * w1.y; az += xv.y * w1.z; aw += xv.y * w1.w;
        float4 w2 = Wl4[(4 * k4 + 2) * 8 + f4];
        ax += xv.z * w2.x; ay += xv.z * w2.y; az += xv.z * w2.z; aw += xv.z * w2.w;
        float4 w3 = Wl4[(4 * k4 + 3) * 8 + f4];
        ax += xv.w * w3.x; ay += xv.w * w3.y; az += xv.w * w3.z; aw += xv.w * w3.w;
    }
    float di = dinv[r];
    unsigned p01 = (unsigned)__half_as_ushort(__float2half(di * ax))
                 | ((unsigned)__half_as_ushort(__float2half(di * ay)) << 16);
    unsigned p23 = (unsigned)__half_as_ushort(__float2half(di * az))
                 | ((unsigned)__half_as_ushort(__float2half(di * aw)) << 16);
    ((uint2*)h1s)[(size_t)r * 8 + f4] = make_uint2(p01, p23);
}

// ---------------- conv1: 8 nodes per wave (R13 structure, unchanged except zero-row write) ----
// lane = q*8 + o: slot q (0..7) owns node c = waveBase + q; o (0..7) owns feat quad [4o,4o+4).

__global__ __launch_bounds__(256) void k_conv1(const int* __restrict__ off, const int* __restrict__ end,
                                               const int* __restrict__ srt, const float* __restrict__ dinv,
                                               const unsigned* __restrict__ h1s,
                                               const float* __restrict__ W2, float* __restrict__ h2s4) {
    int t = threadIdx.x;
    if (blockIdx.x == 0 && t < 4) h2s4[(size_t)N_NODES * 4 + t] = 0.0f;  // zero row for k_conv2 masks
    int lane = t & 63, wid = t >> 6;
    int q = lane >> 3, o = lane & 7;
    int c = (blockIdx.x * 4 + wid) * 8 + q;   // grid = N/32 exactly -> c < N_NODES always

    int b = off[c], e = end[c];
    const char* h1b = (const char*)h1s;
    unsigned oo = (unsigned)(o << 3);
    // self-loop row: independent load, issue before the gather loop
    uint2 sv = *(const uint2*)(h1b + (((unsigned)c << 6) + oo));
    int last = (e > b) ? (e - 1) : b;         // safe clamp index (deg-0 slot reads srt[b], in-bounds)

    float a0a = 0.f, a1a = 0.f, a2a = 0.f, a3a = 0.f;
    float a0b = 0.f, a1b = 0.f, a2b = 0.f, a3b = 0.f;
    float a0c = 0.f, a1c = 0.f, a2c = 0.f, a3c = 0.f;
    float a0d = 0.f, a1d = 0.f, a2d = 0.f, a3d = 0.f;

    int p = b;
    while (__any(p < e)) {
        int i0 = min(p,     last);
        int i1 = min(p + 1, last);
        int i2 = min(p + 2, last);
        int i3 = min(p + 3, last);
        int r0 = srt[i0];
        int r1 = srt[i1];
        int r2 = srt[i2];
        int r3 = srt[i3];
        r0 = (p     < e) ? r0 : N_NODES;      // masked -> zero row
        r1 = (p + 1 < e) ? r1 : N_NODES;
        r2 = (p + 2 < e) ? r2 : N_NODES;
        r3 = (p + 3 < e) ? r3 : N_NODES;
        uint2 v0 = *(const uint2*)(h1b + (((unsigned)r0 << 6) + oo));
        uint2 v1 = *(const uint2*)(h1b + (((unsigned)r1 << 6) + oo));
        uint2 v2 = *(const uint2*)(h1b + (((unsigned)r2 << 6) + oo));
        uint2 v3 = *(const uint2*)(h1b + (((unsigned)r3 << 6) + oo));
        a0a += __low2float(*(const __half2*)&v0.x);  a1a += __high2float(*(const __half2*)&v0.x);
        a2a += __low2float(*(const __half2*)&v0.y);  a3a += __high2float(*(const __half2*)&v0.y);
        a0b += __low2float(*(const __half2*)&v1.x);  a1b += __high2float(*(const __half2*)&v1.x);
        a2b += __low2float(*(const __half2*)&v1.y);  a3b += __high2float(*(const __half2*)&v1.y);
        a0c += __low2float(*(const __half2*)&v2.x);  a1c += __high2float(*(const __half2*)&v2.x);
        a2c += __low2float(*(const __half2*)&v2.y);  a3c += __high2float(*(const __half2*)&v2.y);
        a0d += __low2float(*(const __half2*)&v3.x);  a1d += __high2float(*(const __half2*)&v3.x);
        a2d += __low2float(*(const __half2*)&v3.y);  a3d += __high2float(*(const __half2*)&v3.y);
        p += 4;
    }

    float di = dinv[c];
    float f0 = (a0a + a0b) + (a0c + a0d) + __low2float(*(const __half2*)&sv.x);
    float f1 = (a1a + a1b) + (a1c + a1d) + __high2float(*(const __half2*)&sv.x);
    float f2 = (a2a + a2b) + (a2c + a2d) + __low2float(*(const __half2*)&sv.y);
    float f3 = (a3a + a3b) + (a3c + a3d) + __high2float(*(const __half2*)&sv.y);

    float h0 = fast_tanh(di * f0);
    float h1 = fast_tanh(di * f1);
    float h2 = fast_tanh(di * f2);
    float h3 = fast_tanh(di * f3);

    // W2 rows for feats 4o..4o+3 (loaded post-loop to keep loop VGPR pressure low)
    const float* Wp = W2 + (o << 2) * 3;
    float p0 = h0 * Wp[0] + h1 * Wp[3] + h2 * Wp[6] + h3 * Wp[9];
    float p1 = h0 * Wp[1] + h1 * Wp[4] + h2 * Wp[7] + h3 * Wp[10];
    float p2 = h0 * Wp[2] + h1 * Wp[5] + h2 * Wp[8] + h3 * Wp[11];
#pragma unroll
    for (int m = 1; m <= 4; m <<= 1) {       // reduce over the 8 feat lanes (o), within each slot
        p0 += __shfl_xor(p0, m);
        p1 += __shfl_xor(p1, m);
        p2 += __shfl_xor(p2, m);
    }
    if (o < 4) {
        float vv = (o == 0) ? p0 : (o == 1) ? p1 : (o == 2) ? p2 : 0.0f;
        h2s4[(size_t)c * 4 + o] = (o < 3) ? di * vv : 0.0f;   // slot 3 = real 0
    }
}

// ---------------- conv2 R14: 4 lanes per node, int4 srt loads, zero-row masking ----------------
// 16 nodes/wave (6250 waves vs 100K). Quad j=0..3 of node c streams srt[(b&~3)+16k+4j .. +3]
// as one int4, gathers 4 float4 rows from h2s4 (1.6 MB -> L2-resident), accumulates locally.
// Masked head/tail slots redirect to all-zero row N_NODES (written by k_conv1 block 0).
// int4 over-read past end stays inside the bucket's CAP region (CAP % 4 == 0).
// Epilogue: 2-level butterfly over the quad + 3 coalesced stores.

__global__ __launch_bounds__(256) void k_conv2(const int* __restrict__ off, const int* __restrict__ end,
                                               const int* __restrict__ srt, const float* __restrict__ dinv,
                                               const float* __restrict__ h2s4, float* __restrict__ out) {
    int gt = blockIdx.x * 256 + threadIdx.x;
    int c = gt >> 2, j = gt & 3;
    if (c >= N_NODES) return;

    const float4* h2v = (const float4*)h2s4;
    int b = off[c], e = end[c];
    float4 sv = h2v[c];                      // self-loop term (w component = 0)
    float ax = (j == 0) ? sv.x : 0.0f;
    float ay = (j == 0) ? sv.y : 0.0f;
    float az = (j == 0) ? sv.z : 0.0f;

    int p = (b & ~3) + 4 * j;
    while (p < e) {
        int4 rs = *(const int4*)(srt + p);
        int r0 = (p     >= b && p     < e) ? rs.x : N_NODES;
        int r1 = (p + 1 >= b && p + 1 < e) ? rs.y : N_NODES;
        int r2 = (p + 2 >= b && p + 2 < e) ? rs.z : N_NODES;
        int r3 = (p + 3 >= b && p + 3 < e) ? rs.w : N_NODES;
        float4 v0 = h2v[r0];
        float4 v1 = h2v[r1];
        float4 v2 = h2v[r2];
        float4 v3 = h2v[r3];
        ax += (v0.x + v1.x) + (v2.x + v3.x);
        ay += (v0.y + v1.y) + (v2.y + v3.y);
        az += (v0.z + v1.z) + (v2.z + v3.z);
        p += 16;
    }
#pragma unroll
    for (int m = 1; m <= 2; m <<= 1) {       // reduce over the 4 quad lanes
        ax += __shfl_xor(ax, m);
        ay += __shfl_xor(ay, m);
        az += __shfl_xor(az, m);
    }

    float di = dinv[c];
    if (j < 3) {
        float a = (j == 0) ? ax : (j == 1) ? ay : az;
        out[(size_t)c * 3 + j] = di * a;     // 3 consecutive lanes -> coalesced
    }
}

// ---------------- launch ----------------

extern "C" void kernel_launch(void* const* d_in, const int* in_sizes, int n_in,
                              void* d_out, int out_size, void* d_ws, size_t ws_size,
                              hipStream_t stream) {
    const float* x   = (const float*)d_in[0];
    const int*   ei  = (const int*)d_in[1];  // [2, E] int32
    const float* W1  = (const float*)d_in[2];
    const float* W2  = (const float*)d_in[3];
    float*       out = (float*)d_out;

    const int* row = ei;
    const int* col = ei + N_EDGES;

    char* ws = (char*)d_ws;
    unsigned* bkt = (unsigned*)ws;
    int*      srt = (int*)ws;                 // alias (in-place after k_bucket)
    char*     p   = ws + 4ull * NBKT * CAP;
    int*      gcur = (int*)p;                 p += 4ull * ((NBKT + 63) & ~63);
    int*      off  = (int*)p;                 p += 4ull * N_NODES;
    int*      end  = (int*)p;                 p += 4ull * N_NODES;
    float*    dinv = (float*)p;               p += 4ull * N_NODES;
    unsigned* h1s  = (unsigned*)p;            p += 64ull * (N_NODES + 1);  // +1 zero row
    float*    h2s4 = (float*)p;               // N_NODES+1 rows (zero row for conv2 masks)

    const int B = 256;
    hipMemsetAsync(gcur, 0, 4ull * NBKT, stream);
    hipLaunchKernelGGL(k_part,   dim3(NBLK_E), dim3(512),  0, stream, row, col, gcur, bkt);
    hipLaunchKernelGGL(k_bucket, dim3(NBKT),   dim3(1024), 0, stream, bkt, gcur, off, end, dinv);
    hipLaunchKernelGGL(k_gemm1,  dim3(((N_NODES + 1) * 8 + B - 1) / B), dim3(B), 0, stream, x, W1, dinv, h1s);
    hipLaunchKernelGGL(k_conv1,  dim3(N_NODES / 32), dim3(B), 0, stream,
                       off, end, srt, dinv, h1s, W2, h2s4);
    hipLaunchKernelGGL(k_conv2,  dim3((4 * N_NODES + B - 1) / B), dim3(B), 0, stream,
                       off, end, srt, dinv, h2s4, out);
}